// Round 5
// baseline (164.529 us; speedup 1.0000x reference)
//
#include <hip/hip_runtime.h>
#include <hip/hip_bf16.h>

// ---------------------------------------------------------------------------
// TT-linear, rank-64 factorized, 2 launches:
//   tt_chain_all : cores -> A4t (64x4096 bf16), B4t (4096x64 bf16)
//                  (A-side 64 blocks, B-side 32 blocks; small stages recomputed
//                   redundantly per block in LDS — no serial launch chain)
//   fused_gemm   : per block (16 rows): z = x_rows @ A4 (split-K over 8 waves,
//                  LDS-reduced, bf16 in LDS) then out_rows = z @ B4 + bias.
// HBM floor: read x 131 MB + write out 134 MB ~= 42 us.
// ---------------------------------------------------------------------------

typedef __attribute__((ext_vector_type(8))) short short8;
typedef __attribute__((ext_vector_type(4))) short s16x4;
typedef __attribute__((ext_vector_type(4))) float f32x4;

__device__ __forceinline__ short f2bf(float f) {
    union { float f; unsigned u; } c; c.f = f;
    unsigned u = c.u;
    unsigned r = (u + 0x7fffu + ((u >> 16) & 1u)) >> 16;  // RNE
    return (short)r;
}

// ---------------- chain kernel: all 6 small GEMM stages, 1 launch -----------
// blocks 0..63  (A-side): block b -> A4t rows [b*64, b*64+64) (row=(d0d1d2d3))
//   A2[b][s]   = sum_r c0[(b>>3)*64+r] * c1[(r*8+(b&7))*64+s]        (1 row)
//   A3s[dl][r3]= sum_q A2[b][q] * c2[(q*8+dl)*64+r3]                 (8 rows)
//   A4t[s][b*64+rr] = sum_r A3s[rr>>3][r] * c3[(r*8+(rr&7))*64+s]
// blocks 64..95 (B-side): block cb=b-64 -> d4=cb>>2, j in [(cb&3)*128, +128)
//   B6[q6][d6*8+d7] = sum_q7 c6[(q6*8+d6)*64+q7] * c7[q7*8+d7]
//   B5s[q5][jj] = sum_q6 c5[(q5*8+d5)*64+q6] * B6[q6][j&63],  j=jbase+jj
//   B4t[(d4*512+j)*64+r4] = sum_q5 c4[(r4*8+d4)*64+q5] * B5s[q5][jj]
__global__ __launch_bounds__(256) void tt_chain_all(
    const float* __restrict__ c0, const float* __restrict__ c1,
    const float* __restrict__ c2, const float* __restrict__ c3,
    const float* __restrict__ c4, const float* __restrict__ c5,
    const float* __restrict__ c6, const float* __restrict__ c7,
    short* __restrict__ A4t, short* __restrict__ B4t) {
    __shared__ float smem[64 * 64 + 64 * 128];  // 48 KB
    const int t = threadIdx.x;
    if (blockIdx.x < 64) {
        const int b = blockIdx.x;
        float* A2r = smem;        // 64
        float* A3s = smem + 64;   // 8 x 64
        if (t < 64) {
            const int i1 = b >> 3, d1 = b & 7;
            float acc = 0.f;
            for (int r = 0; r < 64; ++r)
                acc += c0[i1 * 64 + r] * c1[(r * 8 + d1) * 64 + t];
            A2r[t] = acc;
        }
        __syncthreads();
        for (int o = t; o < 512; o += 256) {
            const int dl = o >> 6, r3 = o & 63;
            float acc = 0.f;
            for (int q = 0; q < 64; ++q)
                acc += A2r[q] * c2[(q * 8 + dl) * 64 + r3];
            A3s[o] = acc;
        }
        __syncthreads();
        for (int o = t; o < 4096; o += 256) {
            const int s = o >> 6, rr = o & 63;
            const float* a3 = A3s + ((rr >> 3) << 6);
            const int d3 = rr & 7;
            float acc = 0.f;
            for (int r = 0; r < 64; ++r)
                acc += a3[r] * c3[(r * 8 + d3) * 64 + s];
            A4t[s * 4096 + b * 64 + rr] = f2bf(acc);
        }
    } else {
        const int cb = blockIdx.x - 64;
        const int d4 = cb >> 2, jbase = (cb & 3) << 7;
        float* B6s = smem;          // 64 x 64
        float* B5s = smem + 4096;   // 64 x 128
        for (int o = t; o < 4096; o += 256) {
            const int q6 = o >> 6, dd = o & 63, d6 = dd >> 3, d7 = dd & 7;
            float acc = 0.f;
            for (int q7 = 0; q7 < 64; ++q7)
                acc += c6[(q6 * 8 + d6) * 64 + q7] * c7[q7 * 8 + d7];
            B6s[q6 * 64 + dd] = acc;
        }
        __syncthreads();
        for (int o = t; o < 8192; o += 256) {
            const int q5 = o >> 7, jj = o & 127;
            const int j = jbase + jj, d5 = j >> 6, j2 = j & 63;
            float acc = 0.f;
            for (int q6 = 0; q6 < 64; ++q6)
                acc += c5[(q5 * 8 + d5) * 64 + q6] * B6s[q6 * 64 + j2];
            B5s[q5 * 128 + jj] = acc;
        }
        __syncthreads();
        for (int o = t; o < 8192; o += 256) {
            const int jj = o >> 6, r4 = o & 63;
            float acc = 0.f;
            for (int q5 = 0; q5 < 64; ++q5)
                acc += c4[(r4 * 8 + d4) * 64 + q5] * B5s[q5 * 128 + jj];
            B4t[(d4 * 512 + jbase + jj) * 64 + r4] = f2bf(acc);
        }
    }
}

// ---------------- fused GEMM: out rows = ((x rows) @ A4) @ B4 + bias --------
// 512 blocks x 512 threads (8 waves), 16 rows per block, all co-resident.
__global__ __launch_bounds__(512) void fused_gemm(
    const float* __restrict__ x, const short* __restrict__ A4t,
    const short* __restrict__ B4t, const float* __restrict__ bias,
    float* __restrict__ out) {
    __shared__ float zsm[8 * 1024];   // 32 KB: [wave][row16][col64] partials
    __shared__ short zbl[16 * 64];    // 2 KB: z in bf16
    const int tid = threadIdx.x, wave = tid >> 6, lane = tid & 63;
    const int m0 = blockIdx.x << 4;
    const int r16 = lane & 15, hi = lane >> 4, kq = hi << 3;

    // ---- phase 1: z = x[m0..m0+16) @ A4  (proven round-4 structure) ----
    const float* xp = x + (long)(m0 + r16) * 4000 + kq;
    {
        f32x4 acc[4] = {};
#pragma unroll 2
        for (int t = wave; t < 125; t += 8) {
            const int k0 = t << 5;
            f32x4 u0 = *(const f32x4*)(xp + k0);
            f32x4 u1 = *(const f32x4*)(xp + k0 + 4);
            short8 a;
            a[0] = f2bf(u0[0]); a[1] = f2bf(u0[1]);
            a[2] = f2bf(u0[2]); a[3] = f2bf(u0[3]);
            a[4] = f2bf(u1[0]); a[5] = f2bf(u1[1]);
            a[6] = f2bf(u1[2]); a[7] = f2bf(u1[3]);
#pragma unroll
            for (int f = 0; f < 4; ++f) {
                short8 b = *(const short8*)(A4t + (f * 16 + r16) * 4096 + k0 + kq);
                acc[f] = __builtin_amdgcn_mfma_f32_16x16x32_bf16(a, b, acc[f], 0, 0, 0);
            }
        }
        const int prow = hi << 2;
#pragma unroll
        for (int f = 0; f < 4; ++f)
#pragma unroll
            for (int u = 0; u < 4; ++u)
                zsm[wave * 1024 + (prow + u) * 64 + f * 16 + r16] = acc[f][u];
    }
    __syncthreads();
    if (tid < 256) {
        const f32x4* zp = (const f32x4*)zsm;
        f32x4 s = zp[tid];
#pragma unroll
        for (int w = 1; w < 8; ++w) s += zp[w * 256 + tid];
        s16x4 o2;
#pragma unroll
        for (int u = 0; u < 4; ++u) o2[u] = f2bf(s[u]);
        const int orow = tid >> 4, ocol = (tid & 15) << 2;
        *(s16x4*)(zbl + orow * 64 + ocol) = o2;
    }
    __syncthreads();

    // ---- phase 2: out tile = z(16x64) @ B4t^T + bias (gemm2 frag pattern) --
    short8 az0 = *(const short8*)(zbl + r16 * 64 + kq);        // k = kq..kq+8
    short8 az1 = *(const short8*)(zbl + r16 * 64 + 32 + kq);   // k = 32+kq..
#pragma unroll 2
    for (int ch = 0; ch < 8; ++ch) {
        const int nb = wave * 512 + ch * 64;
#pragma unroll
        for (int j = 0; j < 4; ++j) {
            const int n = nb + j * 16 + r16;
            const short* bp = B4t + n * 64 + kq;
            short8 b0 = *(const short8*)(bp);
            short8 b1 = *(const short8*)(bp + 32);
            f32x4 a = {};
            a = __builtin_amdgcn_mfma_f32_16x16x32_bf16(az0, b0, a, 0, 0, 0);
            a = __builtin_amdgcn_mfma_f32_16x16x32_bf16(az1, b1, a, 0, 0, 0);
            const float bz = bias[n];
#pragma unroll
            for (int u = 0; u < 4; ++u)
                out[(long)(m0 + hi * 4 + u) * 4096 + n] = a[u] + bz;
        }
    }
}

// ---------------------------------------------------------------------------
extern "C" void kernel_launch(void* const* d_in, const int* in_sizes, int n_in,
                              void* d_out, int out_size, void* d_ws, size_t ws_size,
                              hipStream_t stream) {
    const float* x    = (const float*)d_in[0];
    const float* c0   = (const float*)d_in[1];
    const float* c1   = (const float*)d_in[2];
    const float* c2   = (const float*)d_in[3];
    const float* c3   = (const float*)d_in[4];
    const float* c4   = (const float*)d_in[5];
    const float* c5   = (const float*)d_in[6];
    const float* c6   = (const float*)d_in[7];
    const float* c7   = (const float*)d_in[8];
    const float* bias = (const float*)d_in[9];
    float* out = (float*)d_out;

    char* ws = (char*)d_ws;
    short* A4t = (short*)ws;                      // 64*4096*2  = 512 KiB
    short* B4t = (short*)(ws + (512u << 10));     // 4096*64*2  = 512 KiB

    tt_chain_all<<<96, 256, 0, stream>>>(c0, c1, c2, c3, c4, c5, c6, c7,
                                         A4t, B4t);
    fused_gemm<<<512, 512, 0, stream>>>(x, A4t, B4t, bias, out);
}

// Round 6
// 96.086 us; speedup vs baseline: 1.7123x; 1.7123x over previous
//
#include <hip/hip_runtime.h>
#include <hip/hip_bf16.h>

// ---------------------------------------------------------------------------
// TT-linear, rank-64 factorized, 5 launches (all wide-grid):
//   L1 heads   : A2 = c0*c1 (64x64), B6 = c6*c7 (64x64)        [128 blocks]
//   L2 seconds : A3 = A2*c2 (512x64), B5 = B6*c5 (64x512)      [1024 blocks]
//   L3 wide    : A4t (64x4096 bf16), B4t (4096x64 bf16)        [1536 blocks]
//   GEMM1      : zb[8192x64] = x @ A4; 512 blocks x 1024 thr, K split over
//                16 waves, 64 KB LDS reduce -> 32 waves/CU (100% occupancy)
//   GEMM2      : out = zb @ B4t^T + bias, K=64 (proven r4)     [write-bound]
// HBM floor: read x 131 MB + write out 134 MB ~= 42 us.
// ---------------------------------------------------------------------------

typedef __attribute__((ext_vector_type(8))) short short8;
typedef __attribute__((ext_vector_type(4))) short s16x4;
typedef __attribute__((ext_vector_type(4))) float f32x4;

__device__ __forceinline__ short f2bf(float f) {
    union { float f; unsigned u; } c; c.f = f;
    unsigned u = c.u;
    unsigned r = (u + 0x7fffu + ((u >> 16) & 1u)) >> 16;  // RNE
    return (short)r;
}

// ---------------- L1: heads (A2, B6), 128 blocks x 64 threads ---------------
// blocks 0..63 : A2[b][s] = sum_r c0[(b>>3)*64+r] * c1[(r*8+(b&7))*64+s]
// blocks 64..127: B6[r][t] = sum_q c6[(r*8+(t>>3))*64+q] * c7[q*8+(t&7)]
__global__ __launch_bounds__(64) void tt_heads(
    const float* __restrict__ c0, const float* __restrict__ c1,
    const float* __restrict__ c6, const float* __restrict__ c7,
    float* __restrict__ A2, float* __restrict__ B6) {
    const int t = threadIdx.x;
    if (blockIdx.x < 64) {
        const int b = blockIdx.x, i = b >> 3, d = b & 7;
        float acc = 0.f;
        for (int r = 0; r < 64; ++r)
            acc += c0[i * 64 + r] * c1[(r * 8 + d) * 64 + t];
        A2[b * 64 + t] = acc;
    } else {
        const int r = blockIdx.x - 64, d = t >> 3, j = t & 7;
        float acc = 0.f;
        for (int q = 0; q < 64; ++q)
            acc += c6[(r * 8 + d) * 64 + q] * c7[q * 8 + j];
        B6[r * 64 + t] = acc;
    }
}

// ---------------- L2: seconds (A3, B5), 1024 blocks x 64 threads ------------
// blocks 0..511 : A3[row][s] = sum_r A2[(row>>3)*64+r] * c2[(r*8+(row&7))*64+s]
// blocks 512..1023: B5[r*512 + d*64 + j] = sum_q c5[(r*8+d)*64+q] * B6[q*64+j]
__global__ __launch_bounds__(64) void tt_seconds(
    const float* __restrict__ A2, const float* __restrict__ c2,
    const float* __restrict__ B6, const float* __restrict__ c5,
    float* __restrict__ A3, float* __restrict__ B5) {
    const int t = threadIdx.x;
    if (blockIdx.x < 512) {
        const int row = blockIdx.x, i = row >> 3, d = row & 7;
        float acc = 0.f;
        for (int r = 0; r < 64; ++r)
            acc += A2[i * 64 + r] * c2[(r * 8 + d) * 64 + t];
        A3[row * 64 + t] = acc;
    } else {
        const int bb = blockIdx.x - 512, r = bb >> 3, d = bb & 7;
        float acc = 0.f;
        for (int q = 0; q < 64; ++q)
            acc += c5[(r * 8 + d) * 64 + q] * B6[q * 64 + t];
        B5[r * 512 + d * 64 + t] = acc;
    }
}

// ---------------- L3: wide final steps, bf16 transposed (proven r3/r4) ------
// blocks [0,1024):   A4t[s][row] = f2bf( sum_r A3[row>>3][r]*c3[(r*8+d)*64+s] )
// blocks [1024,1536): B4t[(d*512+j)][r] = f2bf( sum_q c4[(r*8+d)*64+q]*B5[q][j] )
__global__ __launch_bounds__(256) void tt_chain_wide(
    const float* __restrict__ A3, const float* __restrict__ c3,
    const float* __restrict__ B5, const float* __restrict__ c4,
    short* __restrict__ A4t, short* __restrict__ B4t) {
    const int bid = blockIdx.x, t = threadIdx.x;
    if (bid < 1024) {
        const int row = (bid << 2) | (t >> 6);
        const int s = t & 63;
        const int i = row >> 3, d = row & 7;
        float acc = 0.f;
        for (int r = 0; r < 64; ++r)
            acc += A3[i * 64 + r] * c3[(r * 8 + d) * 64 + s];
        A4t[s * 4096 + row] = f2bf(acc);
    } else {
        const int rd = bid - 1024;
        const int r = rd >> 3, d = rd & 7;
        for (int j = t; j < 512; j += 256) {
            float acc = 0.f;
            for (int q = 0; q < 64; ++q)
                acc += c4[(r * 8 + d) * 64 + q] * B5[q * 512 + j];
            B4t[(d * 512 + j) * 64 + r] = f2bf(acc);
        }
    }
}

// ---------------- GEMM1: zb = f2bf(x @ A4), 512 blocks x 1024 threads -------
// Block owns 16 rows; 16 waves split the 125 k-tiles (4000 = 125*32);
// f32 partials reduced through 64 KB LDS.  2 blocks/CU -> 100% occupancy.
__global__ __launch_bounds__(1024, 8) void gemm1_v2(
    const float* __restrict__ x, const short* __restrict__ A4t,
    short* __restrict__ zb) {
    __shared__ float zsm[16 * 1024];  // 64 KB: [wave][row16][col64]
    const int tid = threadIdx.x, wave = tid >> 6, lane = tid & 63;
    const int m0 = blockIdx.x << 4;
    const int r16 = lane & 15, hi = lane >> 4, kq = hi << 3;
    const float* xp = x + (long)(m0 + r16) * 4000 + kq;

    f32x4 acc[4] = {};
#pragma unroll 2
    for (int t = wave; t < 125; t += 16) {
        const int k0 = t << 5;
        f32x4 u0 = *(const f32x4*)(xp + k0);
        f32x4 u1 = *(const f32x4*)(xp + k0 + 4);
        short8 a;
        a[0] = f2bf(u0[0]); a[1] = f2bf(u0[1]);
        a[2] = f2bf(u0[2]); a[3] = f2bf(u0[3]);
        a[4] = f2bf(u1[0]); a[5] = f2bf(u1[1]);
        a[6] = f2bf(u1[2]); a[7] = f2bf(u1[3]);
#pragma unroll
        for (int f = 0; f < 4; ++f) {
            short8 b = *(const short8*)(A4t + (f * 16 + r16) * 4096 + k0 + kq);
            acc[f] = __builtin_amdgcn_mfma_f32_16x16x32_bf16(a, b, acc[f], 0, 0, 0);
        }
    }
    // C/D layout: col = f*16 + (lane&15), row = (lane>>4)*4 + u
    const int prow = hi << 2;
#pragma unroll
    for (int f = 0; f < 4; ++f)
#pragma unroll
        for (int u = 0; u < 4; ++u)
            zsm[wave * 1024 + (prow + u) * 64 + f * 16 + r16] = acc[f][u];
    __syncthreads();
    if (tid < 256) {
        const f32x4* zp = (const f32x4*)zsm;  // 256 f32x4 per wave-slab
        f32x4 s = zp[tid];
#pragma unroll
        for (int w = 1; w < 16; ++w) s += zp[w * 256 + tid];
        s16x4 o;
#pragma unroll
        for (int u = 0; u < 4; ++u) o[u] = f2bf(s[u]);
        const int orow = tid >> 4, ocol = (tid & 15) << 2;
        *(s16x4*)(zb + (m0 + orow) * 64 + ocol) = o;
    }
}

// ---------------- GEMM2: C = zb(8192xK) * B4t(4096xK)^T + bias (proven r4) --
#define BM 128
#define BN 128
#define BK 32

template <int K>
__global__ __launch_bounds__(256) void gemm_bias_kernel(
    const short* __restrict__ A,    // M x K bf16
    const short* __restrict__ Bt,   // N x K bf16
    const float* __restrict__ bias,
    float* __restrict__ C) {
    constexpr int N = 4096;
    __shared__ short As[BM * BK];
    __shared__ short Bs[BN * BK];

    const int tid  = threadIdx.x;
    const int wave = tid >> 6;
    const int lane = tid & 63;

    const int bid = blockIdx.x;
    const int wg  = (bid & 7) * 256 + (bid >> 3);  // 2048 % 8 == 0, bijective
    const int m0 = (wg >> 5) * BM;
    const int n0 = (wg & 31) * BN;

    const int c0i = tid;
    const int c1i = 256 + tid;
    const short* gA0 = A  + (m0 + (c0i >> 2)) * K + ((c0i & 3) << 3);
    const short* gA1 = A  + (m0 + (c1i >> 2)) * K + ((c1i & 3) << 3);
    const short* gB0 = Bt + (n0 + (c0i >> 2)) * K + ((c0i & 3) << 3);
    const short* gB1 = Bt + (n0 + (c1i >> 2)) * K + ((c1i & 3) << 3);
    short* lA0 = As + wave * 512;
    short* lA1 = As + 2048 + wave * 512;
    short* lB0 = Bs + wave * 512;
    short* lB1 = Bs + 2048 + wave * 512;

    const int wr = (wave >> 1) << 6;
    const int wc = (wave & 1) << 6;
    const int r16 = lane & 15;
    const int kq  = (lane >> 4) << 3;

    f32x4 acc[4][4] = {};

    for (int kt = 0; kt < K / BK; ++kt) {
        __builtin_amdgcn_global_load_lds((const __attribute__((address_space(1))) void*)gA0,
                                         (__attribute__((address_space(3))) void*)lA0, 16, 0, 0);
        __builtin_amdgcn_global_load_lds((const __attribute__((address_space(1))) void*)gA1,
                                         (__attribute__((address_space(3))) void*)lA1, 16, 0, 0);
        __builtin_amdgcn_global_load_lds((const __attribute__((address_space(1))) void*)gB0,
                                         (__attribute__((address_space(3))) void*)lB0, 16, 0, 0);
        __builtin_amdgcn_global_load_lds((const __attribute__((address_space(1))) void*)gB1,
                                         (__attribute__((address_space(3))) void*)lB1, 16, 0, 0);
        gA0 += BK; gA1 += BK; gB0 += BK; gB1 += BK;
        __syncthreads();

        short8 a[4], b[4];
#pragma unroll
        for (int f = 0; f < 4; ++f) {
            a[f] = *(const short8*)(As + (wr + f * 16 + r16) * BK + kq);
            b[f] = *(const short8*)(Bs + (wc + f * 16 + r16) * BK + kq);
        }
#pragma unroll
        for (int i = 0; i < 4; ++i)
#pragma unroll
            for (int j = 0; j < 4; ++j)
                acc[i][j] = __builtin_amdgcn_mfma_f32_16x16x32_bf16(
                    a[i], b[j], acc[i][j], 0, 0, 0);
        __syncthreads();
    }

    const int crow = m0 + wr + ((lane >> 4) << 2);
    const int ccol = n0 + wc + r16;
#pragma unroll
    for (int i = 0; i < 4; ++i) {
#pragma unroll
        for (int j = 0; j < 4; ++j) {
            const int r = crow + i * 16;
            const int c = ccol + j * 16;
            const float bz = bias[c];
#pragma unroll
            for (int u = 0; u < 4; ++u)
                C[(r + u) * N + c] = acc[i][j][u] + bz;
        }
    }
}

// ---------------------------------------------------------------------------
extern "C" void kernel_launch(void* const* d_in, const int* in_sizes, int n_in,
                              void* d_out, int out_size, void* d_ws, size_t ws_size,
                              hipStream_t stream) {
    const float* x    = (const float*)d_in[0];
    const float* c0   = (const float*)d_in[1];
    const float* c1   = (const float*)d_in[2];
    const float* c2   = (const float*)d_in[3];
    const float* c3   = (const float*)d_in[4];
    const float* c4   = (const float*)d_in[5];
    const float* c5   = (const float*)d_in[6];
    const float* c6   = (const float*)d_in[7];
    const float* c7   = (const float*)d_in[8];
    const float* bias = (const float*)d_in[9];
    float* out = (float*)d_out;

    char* ws = (char*)d_ws;
    short* zb  = (short*)ws;                               // 8192*64*2 = 1 MiB
    short* A4t = (short*)(ws + (1u << 20));                // 64*4096*2 = 512 KiB
    short* B4t = (short*)(ws + (1u << 20) + (512u << 10)); // 4096*64*2 = 512 KiB
    float* A2  = (float*)(ws + (2u << 20));                // 64*64
    float* A3  = A2 + 64 * 64;                             // 512*64
    float* B6  = A3 + 512 * 64;                            // 64*64
    float* B5  = B6 + 64 * 64;                             // 64*512

    tt_heads<<<128, 64, 0, stream>>>(c0, c1, c6, c7, A2, B6);
    tt_seconds<<<1024, 64, 0, stream>>>(A2, c2, B6, c5, A3, B5);
    tt_chain_wide<<<1536, 256, 0, stream>>>(A3, c3, B5, c4, A4t, B4t);

    gemm1_v2<<<512, 1024, 0, stream>>>(x, A4t, zb);
    gemm_bias_kernel<64><<<2048, 256, 0, stream>>>(zb, B4t, bias, out);
}

// Round 8
// 81.624 us; speedup vs baseline: 2.0157x; 1.1772x over previous
//
#include <hip/hip_runtime.h>
#include <hip/hip_bf16.h>

// ---------------------------------------------------------------------------
// TT-linear, rank-64 factorized, 5 launches (all wide-grid):
//   L1 heads   : A2 = c0*c1 (64x64), B6 = c6*c7 (64x64)        [128 blocks]
//   L2 seconds : A3 = A2*c2 (512x64), B5 = B6*c5 (64x512)      [1024 blocks]
//   L3 wide    : A4f (MFMA-fragment-ordered bf16), B4t (4096x64 bf16)
//   GEMM1      : zb[8192x64] = x @ A4; 512 blocks x 1024 thr, 100% occupancy,
//                B-operand loads lane-contiguous via A4f layout
//   GEMM2      : out = zb @ B4t^T + bias, K=64; LDS-staged epilogue
//                (write -> __syncthreads -> read: the r7 version raced) for
//                256B-contiguous f32x4 stores
// HBM floor: read x 131 MB + write out 134 MB ~= 42 us.
// ---------------------------------------------------------------------------

typedef __attribute__((ext_vector_type(8))) short short8;
typedef __attribute__((ext_vector_type(4))) short s16x4;
typedef __attribute__((ext_vector_type(4))) float f32x4;

__device__ __forceinline__ short f2bf(float f) {
    union { float f; unsigned u; } c; c.f = f;
    unsigned u = c.u;
    unsigned r = (u + 0x7fffu + ((u >> 16) & 1u)) >> 16;  // RNE
    return (short)r;
}

// ---------------- L1: heads (A2, B6), 128 blocks x 64 threads ---------------
__global__ __launch_bounds__(64) void tt_heads(
    const float* __restrict__ c0, const float* __restrict__ c1,
    const float* __restrict__ c6, const float* __restrict__ c7,
    float* __restrict__ A2, float* __restrict__ B6) {
    const int t = threadIdx.x;
    if (blockIdx.x < 64) {
        const int b = blockIdx.x, i = b >> 3, d = b & 7;
        float acc = 0.f;
        for (int r = 0; r < 64; ++r)
            acc += c0[i * 64 + r] * c1[(r * 8 + d) * 64 + t];
        A2[b * 64 + t] = acc;
    } else {
        const int r = blockIdx.x - 64, d = t >> 3, j = t & 7;
        float acc = 0.f;
        for (int q = 0; q < 64; ++q)
            acc += c6[(r * 8 + d) * 64 + q] * c7[q * 8 + j];
        B6[r * 64 + t] = acc;
    }
}

// ---------------- L2: seconds (A3, B5), 1024 blocks x 64 threads ------------
__global__ __launch_bounds__(64) void tt_seconds(
    const float* __restrict__ A2, const float* __restrict__ c2,
    const float* __restrict__ B6, const float* __restrict__ c5,
    float* __restrict__ A3, float* __restrict__ B5) {
    const int t = threadIdx.x;
    if (blockIdx.x < 512) {
        const int row = blockIdx.x, i = row >> 3, d = row & 7;
        float acc = 0.f;
        for (int r = 0; r < 64; ++r)
            acc += A2[i * 64 + r] * c2[(r * 8 + d) * 64 + t];
        A3[row * 64 + t] = acc;
    } else {
        const int bb = blockIdx.x - 512, r = bb >> 3, d = bb & 7;
        float acc = 0.f;
        for (int q = 0; q < 64; ++q)
            acc += c5[(r * 8 + d) * 64 + q] * B6[q * 64 + t];
        B5[r * 512 + d * 64 + t] = acc;
    }
}

// ---------------- L3: wide final steps ---------------------------------------
// blocks [0,1024): A4f fragment-ordered:
//   value A4[k][s] (k = input-feature, s = rank) lands at
//   A4f[((k>>5)*4 + (s>>4))*512 + ((k>>3)&3)*128 + (s&15)*8 + (k&7)]
//   so gemm1's b-frag load for (tile t, f) is lane-contiguous:
//   A4f + ((t*4+f)<<9) + lane*8  (lane = hi*16 + r16)
// blocks [1024,1536): B4t[(d*512+j)][r] = f2bf( sum_q c4[(r*8+d)*64+q]*B5[q][j] )
__global__ __launch_bounds__(256) void tt_chain_wide(
    const float* __restrict__ A3, const float* __restrict__ c3,
    const float* __restrict__ B5, const float* __restrict__ c4,
    short* __restrict__ A4f, short* __restrict__ B4t) {
    const int bid = blockIdx.x, t = threadIdx.x;
    if (bid < 1024) {
        const int k = (bid << 2) | (t >> 6);   // input-feature index 0..4095
        const int s = t & 63;                  // rank index 0..63
        const int i = k >> 3, d = k & 7;
        float acc = 0.f;
        for (int r = 0; r < 64; ++r)
            acc += A3[i * 64 + r] * c3[(r * 8 + d) * 64 + s];
        A4f[(((k >> 5) * 4 + (s >> 4)) << 9) + (((k >> 3) & 3) << 7) +
            ((s & 15) << 3) + (k & 7)] = f2bf(acc);
    } else {
        const int rd = bid - 1024;
        const int r = rd >> 3, d = rd & 7;
        for (int j = t; j < 512; j += 256) {
            float acc = 0.f;
            for (int q = 0; q < 64; ++q)
                acc += c4[(r * 8 + d) * 64 + q] * B5[q * 512 + j];
            B4t[(d * 512 + j) * 64 + r] = f2bf(acc);
        }
    }
}

// ---------------- GEMM1: zb = f2bf(x @ A4), 512 blocks x 1024 threads -------
// Block owns 16 rows; 16 waves split the 125 k-tiles (4000 = 125*32);
// f32 partials reduced through 64 KB LDS.  2 blocks/CU -> 100% occupancy.
__global__ __launch_bounds__(1024, 8) void gemm1_v2(
    const float* __restrict__ x, const short* __restrict__ A4f,
    short* __restrict__ zb) {
    __shared__ float zsm[16 * 1024];  // 64 KB: [wave][row16][col64]
    const int tid = threadIdx.x, wave = tid >> 6, lane = tid & 63;
    const int m0 = blockIdx.x << 4;
    const int r16 = lane & 15, hi = lane >> 4, kq = hi << 3;
    const float* xp = x + (long)(m0 + r16) * 4000 + kq;
    const short* a4p = A4f + (lane << 3);

    f32x4 acc[4] = {};
#pragma unroll 2
    for (int t = wave; t < 125; t += 16) {
        const int k0 = t << 5;
        f32x4 u0 = *(const f32x4*)(xp + k0);
        f32x4 u1 = *(const f32x4*)(xp + k0 + 4);
        short8 a;
        a[0] = f2bf(u0[0]); a[1] = f2bf(u0[1]);
        a[2] = f2bf(u0[2]); a[3] = f2bf(u0[3]);
        a[4] = f2bf(u1[0]); a[5] = f2bf(u1[1]);
        a[6] = f2bf(u1[2]); a[7] = f2bf(u1[3]);
#pragma unroll
        for (int f = 0; f < 4; ++f) {
            short8 b = *(const short8*)(a4p + (((t << 2) + f) << 9));
            acc[f] = __builtin_amdgcn_mfma_f32_16x16x32_bf16(a, b, acc[f], 0, 0, 0);
        }
    }
    // C/D layout: col = f*16 + (lane&15), row = (lane>>4)*4 + u
    const int prow = hi << 2;
#pragma unroll
    for (int f = 0; f < 4; ++f)
#pragma unroll
        for (int u = 0; u < 4; ++u)
            zsm[wave * 1024 + (prow + u) * 64 + f * 16 + r16] = acc[f][u];
    __syncthreads();
    if (tid < 256) {
        const f32x4* zp = (const f32x4*)zsm;  // 256 f32x4 per wave-slab
        f32x4 s = zp[tid];
#pragma unroll
        for (int w = 1; w < 16; ++w) s += zp[w * 256 + tid];
        s16x4 o;
#pragma unroll
        for (int u = 0; u < 4; ++u) o[u] = f2bf(s[u]);
        const int orow = tid >> 4, ocol = (tid & 15) << 2;
        *(s16x4*)(zb + (m0 + orow) * 64 + ocol) = o;
    }
}

// ---------------- GEMM2: C = zb(8192xK) * B4t(4096xK)^T + bias --------------
// LDS-staged epilogue with explicit barriers (write -> barrier -> read) so the
// cross-lane transpose is race-free; stores are lane-contiguous f32x4 (256B).
#define BM 128
#define BN 128
#define BK 32

template <int K>
__global__ __launch_bounds__(256) void gemm_bias_kernel(
    const short* __restrict__ A,    // M x K bf16
    const short* __restrict__ Bt,   // N x K bf16
    const float* __restrict__ bias,
    float* __restrict__ C) {
    constexpr int N = 4096;
    __shared__ __align__(16) char smem[16384];  // staging (8K+8K), epilogue 16K
    short* As = (short*)smem;
    short* Bs = (short*)(smem + 8192);
    float* eps = (float*)smem;

    const int tid  = threadIdx.x;
    const int wave = tid >> 6;
    const int lane = tid & 63;

    const int bid = blockIdx.x;
    const int wg  = (bid & 7) * 256 + (bid >> 3);  // 2048 % 8 == 0, bijective
    const int m0 = (wg >> 5) * BM;
    const int n0 = (wg & 31) * BN;

    const int c0i = tid;
    const int c1i = 256 + tid;
    const short* gA0 = A  + (m0 + (c0i >> 2)) * K + ((c0i & 3) << 3);
    const short* gA1 = A  + (m0 + (c1i >> 2)) * K + ((c1i & 3) << 3);
    const short* gB0 = Bt + (n0 + (c0i >> 2)) * K + ((c0i & 3) << 3);
    const short* gB1 = Bt + (n0 + (c1i >> 2)) * K + ((c1i & 3) << 3);
    short* lA0 = As + wave * 512;
    short* lA1 = As + 2048 + wave * 512;
    short* lB0 = Bs + wave * 512;
    short* lB1 = Bs + 2048 + wave * 512;

    const int wr = (wave >> 1) << 6;
    const int wc = (wave & 1) << 6;
    const int r16 = lane & 15;
    const int hi  = lane >> 4;
    const int kq  = hi << 3;

    f32x4 acc[4][4] = {};

    for (int kt = 0; kt < K / BK; ++kt) {
        __builtin_amdgcn_global_load_lds((const __attribute__((address_space(1))) void*)gA0,
                                         (__attribute__((address_space(3))) void*)lA0, 16, 0, 0);
        __builtin_amdgcn_global_load_lds((const __attribute__((address_space(1))) void*)gA1,
                                         (__attribute__((address_space(3))) void*)lA1, 16, 0, 0);
        __builtin_amdgcn_global_load_lds((const __attribute__((address_space(1))) void*)gB0,
                                         (__attribute__((address_space(3))) void*)lB0, 16, 0, 0);
        __builtin_amdgcn_global_load_lds((const __attribute__((address_space(1))) void*)gB1,
                                         (__attribute__((address_space(3))) void*)lB1, 16, 0, 0);
        gA0 += BK; gA1 += BK; gB0 += BK; gB1 += BK;
        __syncthreads();

        short8 a[4], b[4];
#pragma unroll
        for (int f = 0; f < 4; ++f) {
            a[f] = *(const short8*)(As + (wr + f * 16 + r16) * BK + kq);
            b[f] = *(const short8*)(Bs + (wc + f * 16 + r16) * BK + kq);
        }
#pragma unroll
        for (int i = 0; i < 4; ++i)
#pragma unroll
            for (int j = 0; j < 4; ++j)
                acc[i][j] = __builtin_amdgcn_mfma_f32_16x16x32_bf16(
                    a[i], b[j], acc[i][j], 0, 0, 0);
        __syncthreads();
    }

    // ---- epilogue: LDS transpose (barriered) -> 256B-contiguous stores -----
    float* slab = eps + wave * 1024;  // per-wave 4 KB slab
    const f32x4 bzv = *(const f32x4*)(bias + n0 + wc + (r16 << 2));
#pragma unroll
    for (int i = 0; i < 4; ++i) {
        __syncthreads();   // previous iteration's reads (and K-loop) complete
#pragma unroll
        for (int j = 0; j < 4; ++j)
#pragma unroll
            for (int u = 0; u < 4; ++u)
                slab[((hi << 2) + u) * 64 + j * 16 + r16] = acc[i][j][u];
        __syncthreads();   // cross-lane transpose: writes visible to reads
#pragma unroll
        for (int c = 0; c < 4; ++c) {
            const int lrow = (c << 2) + hi;                 // 0..15
            f32x4 v = *(const f32x4*)(slab + lrow * 64 + (r16 << 2));
            v += bzv;
            const long row = m0 + wr + i * 16 + lrow;
            *(f32x4*)(C + row * N + n0 + wc + (r16 << 2)) = v;
        }
    }
}

// ---------------------------------------------------------------------------
extern "C" void kernel_launch(void* const* d_in, const int* in_sizes, int n_in,
                              void* d_out, int out_size, void* d_ws, size_t ws_size,
                              hipStream_t stream) {
    const float* x    = (const float*)d_in[0];
    const float* c0   = (const float*)d_in[1];
    const float* c1   = (const float*)d_in[2];
    const float* c2   = (const float*)d_in[3];
    const float* c3   = (const float*)d_in[4];
    const float* c4   = (const float*)d_in[5];
    const float* c5   = (const float*)d_in[6];
    const float* c6   = (const float*)d_in[7];
    const float* c7   = (const float*)d_in[8];
    const float* bias = (const float*)d_in[9];
    float* out = (float*)d_out;

    char* ws = (char*)d_ws;
    short* zb  = (short*)ws;                               // 8192*64*2 = 1 MiB
    short* A4f = (short*)(ws + (1u << 20));                // 512 KiB (frag-ordered)
    short* B4t = (short*)(ws + (1u << 20) + (512u << 10)); // 4096*64*2 = 512 KiB
    float* A2  = (float*)(ws + (2u << 20));                // 64*64
    float* A3  = A2 + 64 * 64;                             // 512*64
    float* B6  = A3 + 512 * 64;                            // 64*64
    float* B5  = B6 + 64 * 64;                             // 64*512

    tt_heads<<<128, 64, 0, stream>>>(c0, c1, c6, c7, A2, B6);
    tt_seconds<<<1024, 64, 0, stream>>>(A2, c2, B6, c5, A3, B5);
    tt_chain_wide<<<1536, 256, 0, stream>>>(A3, c3, B5, c4, A4f, B4t);

    gemm1_v2<<<512, 1024, 0, stream>>>(x, A4f, zb);
    gemm_bias_kernel<64><<<2048, 256, 0, stream>>>(zb, B4t, bias, out);
}